// Round 8
// baseline (1567.085 us; speedup 1.0000x reference)
//
#include <hip/hip_runtime.h>
#include <hip/hip_bf16.h>
#include <cstdint>
#include <cmath>

typedef __bf16 bf16;
typedef __attribute__((ext_vector_type(8))) __bf16 bf16x8;
typedef __attribute__((ext_vector_type(4))) __bf16 bf16x4;
typedef __attribute__((ext_vector_type(4))) float f32x4;

// async global->LDS, 16B per lane, dest = wave-uniform base (+ lane*16 by HW)
__device__ __forceinline__ void gload_lds16(const void* g, void* l) {
  __builtin_amdgcn_global_load_lds((__attribute__((address_space(1))) void*)g,
                                   (__attribute__((address_space(3))) void*)l,
                                   16, 0, 0);
}

// ---------------------------------------------------------------------------
// Occupancy-first drift GEMM: 128x256 tile, BK=32, 8 waves (4M x 2N: wave =
// 32 rows x 128 cols), acc[2][8]=64 regs -> ~120 VGPR/wave -> 2 blocks/CU.
// Double-buffered LDS (2 x 24KB), ONE __syncthreads per K-tile, full-tile
// prefetch front-loaded. Two independent blocks/CU interleave port vs MFMA.
// C = A[M,K] @ Bt^T (Bt stored [N][K] bf16).
// LDS rows are 64B (4 chunks of 16B); stored chunk = (logical + (r>>1)) & 3
// -> 2-way bank aliasing on ds_read_b128 (free) and linear staging writes.
// EPI 1: f32 = acc+bias[col]+resid       (Wo)
// EPI 2: f32 = acc+resid                 (W3)
// EPI 3: QKV fused RoPE + head reorder: q,k -> [h][s][128], v -> [h][128][s]
// EPI 4: FF fused SwiGLU on 16-interleaved W1/W2 -> g [s][11008]
// ---------------------------------------------------------------------------
template<int EPI>
__global__ __launch_bounds__(512, 4) void gemmd(
    const bf16* __restrict__ A, const bf16* __restrict__ Bt, void* __restrict__ Cv,
    const float* __restrict__ bias, const float* __restrict__ resid,
    const float* __restrict__ cosT, const float* __restrict__ sinT,
    bf16* __restrict__ q_out, bf16* __restrict__ k_out, bf16* __restrict__ v_out,
    int M, int N, int K, int gm) {
  extern __shared__ char lds[];
  constexpr int BM = 128;
  constexpr int ASZ = BM * 64;        // 8 KB (128 rows x 64B)
  constexpr int BUFS = ASZ + 16384;   // 24 KB per buffer (B = 256 rows x 64B)

  const int tid = threadIdx.x;
  const int wave = tid >> 6, lane = tid & 63;
  const int wr = wave >> 1, wc = wave & 1;   // 4M x 2N wave grid
  const int l15 = lane & 15, l4 = lane >> 4;
  // XCD-aware swizzle (grids are multiples of 8)
  const int qq = gridDim.x >> 3;
  const int wgid = (blockIdx.x & 7) * qq + (blockIdx.x >> 3);
  const int tm = wgid % gm, tn = wgid / gm;
  const long brow = (long)tm * BM, bcol = (long)tn * 256;
  const int NT = K >> 5;
  const bf16* Ab = A + brow * K;
  const bf16* Bb = Bt + bcol * K;

  f32x4 acc[2][8];
  #pragma unroll
  for (int i = 0; i < 2; ++i)
    #pragma unroll
    for (int j = 0; j < 8; ++j) acc[i][j] = (f32x4){0.f, 0.f, 0.f, 0.f};

  bf16x8 a[2], b[8];

  // staging: A 512 slots (1/thread), B 1024 slots (2/thread); slot = r*4 + cs
  const int sa_r = tid >> 2, sa_cs = tid & 3;
  const long aoff = (long)sa_r * K + (((sa_cs - (sa_r >> 1)) & 3) << 3);
  auto stage = [&](int T) {
    const long kofs = (long)T << 5;
    char* wb = lds + (T & 1) * BUFS;
    gload_lds16(Ab + aoff + kofs, wb + tid * 16);
    #pragma unroll
    for (int i = 0; i < 2; ++i) {
      const int slot = i * 512 + tid, r = slot >> 2, cs = slot & 3;
      gload_lds16(Bb + (long)r * K + kofs + (((cs - (r >> 1)) & 3) << 3),
                  wb + ASZ + slot * 16);
    }
  };

  stage(0);
  __syncthreads();

  for (int g = 0; g < NT; ++g) {
    const int pg = (g & 1) * BUFS;
    if (g + 1 < NT) stage(g + 1);   // writes opposite buffer; fenced by barrier
    #pragma unroll
    for (int nf = 0; nf < 8; ++nf) {
      const int r = wc * 128 + nf * 16 + l15;
      b[nf] = *(const bf16x8*)(lds + pg + ASZ + r * 64 + (((l4 + (r >> 1)) & 3) << 4));
    }
    #pragma unroll
    for (int mf = 0; mf < 2; ++mf) {
      const int r = wr * 32 + mf * 16 + l15;
      a[mf] = *(const bf16x8*)(lds + pg + r * 64 + (((l4 + (r >> 1)) & 3) << 4));
    }
    __builtin_amdgcn_s_setprio(1);
    #pragma unroll
    for (int mf = 0; mf < 2; ++mf)
      #pragma unroll
      for (int nf = 0; nf < 8; ++nf)
        acc[mf][nf] = __builtin_amdgcn_mfma_f32_16x16x32_bf16(
            a[mf], b[nf], acc[mf][nf], 0, 0, 0);
    __builtin_amdgcn_s_setprio(0);
    __syncthreads();
  }

  // ------------------------------- epilogues -------------------------------
  if (EPI == 1 || EPI == 2) {
    #pragma unroll
    for (int mf = 0; mf < 2; ++mf) {
      const long row0 = brow + wr * 32 + mf * 16 + l4 * 4;
      #pragma unroll
      for (int nf = 0; nf < 8; ++nf) {
        const long col = bcol + wc * 128 + nf * 16 + l15;
        #pragma unroll
        for (int rj = 0; rj < 4; ++rj) {
          const long idx = (row0 + rj) * N + col;
          const float v = acc[mf][nf][rj];
          if (EPI == 1) ((float*)Cv)[idx] = v + bias[col] + resid[idx];
          else          ((float*)Cv)[idx] = v + resid[idx];
        }
      }
    }
  } else if (EPI == 3) {
    const int region = (int)(bcol >> 12);           // 0=Q, 1=K, 2=V
    const int hc = (int)(bcol & 4095) + wc * 128;   // head-space col base
    const int h = hc >> 7;
    if (region < 2) {
      bf16* dh = (region == 0 ? q_out : k_out) + (long)h * 2048 * 128;
      #pragma unroll
      for (int mf = 0; mf < 2; ++mf) {
        #pragma unroll
        for (int rj = 0; rj < 4; ++rj) {
          const int s = (int)brow + wr * 32 + mf * 16 + l4 * 4 + rj;
          const float* cr = cosT + s * 64;
          const float* sr = sinT + s * 64;
          #pragma unroll
          for (int nfp = 0; nfp < 4; ++nfp) {
            const int d = nfp * 16 + l15;
            const float c = cr[d], sn = sr[d];
            const float x1 = acc[mf][nfp][rj], x2 = acc[mf][nfp + 4][rj];
            dh[(long)s * 128 + d]      = (bf16)(x1 * c - x2 * sn);
            dh[(long)s * 128 + d + 64] = (bf16)(x2 * c + x1 * sn);
          }
        }
      }
    } else {
      bf16* dh = v_out + (long)h * 128 * 2048;
      #pragma unroll
      for (int mf = 0; mf < 2; ++mf) {
        const int s0 = (int)brow + wr * 32 + mf * 16 + l4 * 4;
        #pragma unroll
        for (int nf = 0; nf < 8; ++nf) {
          const int d = nf * 16 + l15;
          bf16x4 v;
          #pragma unroll
          for (int rj = 0; rj < 4; ++rj) v[rj] = (bf16)acc[mf][nf][rj];
          *(bf16x4*)(dh + (long)d * 2048 + s0) = v;
        }
      }
    }
  } else {  // EPI == 4: fused SwiGLU, interleaved W12 columns -> g [s][11008]
    #pragma unroll
    for (int mf = 0; mf < 2; ++mf) {
      #pragma unroll
      for (int rj = 0; rj < 4; ++rj) {
        const int s = (int)brow + wr * 32 + mf * 16 + l4 * 4 + rj;
        bf16* gr = (bf16*)Cv + (long)s * 11008;
        #pragma unroll
        for (int nfp = 0; nfp < 4; ++nfp) {
          const int col = (int)bcol + wc * 128 + nfp * 32 + l15;
          const int j = ((col >> 5) << 4) + l15;
          const float x1 = acc[mf][2 * nfp][rj], x2 = acc[mf][2 * nfp + 1][rj];
          const float sg = x1 / (1.f + __expf(-x1));
          gr[j] = (bf16)(sg * x2);
        }
      }
    }
  }
}

// ---------------------------------------------------------------------------
// RMSNorm: one block per row of [2048][4096] f32 -> bf16
// ---------------------------------------------------------------------------
__global__ __launch_bounds__(256) void rmsnorm_kernel(
    const float* __restrict__ X, const float* __restrict__ gamma,
    bf16* __restrict__ out, int D) {
  const int row = blockIdx.x;
  const float* xr = X + (long)row * D;
  float ss = 0.f;
  for (int i = threadIdx.x * 4; i < D; i += 1024) {
    float4 v = *(const float4*)(xr + i);
    ss += v.x * v.x + v.y * v.y + v.z * v.z + v.w * v.w;
  }
  #pragma unroll
  for (int off = 32; off; off >>= 1) ss += __shfl_down(ss, off, 64);
  __shared__ float wsum[4];
  if ((threadIdx.x & 63) == 0) wsum[threadIdx.x >> 6] = ss;
  __syncthreads();
  const float tot = wsum[0] + wsum[1] + wsum[2] + wsum[3];
  const float scale = rsqrtf(1e-7f + tot / (float)D);
  bf16* orow = out + (long)row * D;
  for (int i = threadIdx.x * 4; i < D; i += 1024) {
    float4 v = *(const float4*)(xr + i);
    float4 g = *(const float4*)(gamma + i);
    orow[i]     = (bf16)(v.x * scale * g.x);
    orow[i + 1] = (bf16)(v.y * scale * g.y);
    orow[i + 2] = (bf16)(v.z * scale * g.z);
    orow[i + 3] = (bf16)(v.w * scale * g.w);
  }
}

// ---------------------------------------------------------------------------
// Vectorized weight transpose + f32->bf16: in [R][C] f32 -> out [C][R] bf16.
// ---------------------------------------------------------------------------
__global__ __launch_bounds__(256) void wtrans_kernel(
    const float* __restrict__ in, bf16* __restrict__ out, int R, int C) {
  __shared__ float t[64][65];
  const int bx = blockIdx.x, by = blockIdx.y;  // bx: C-tile, by: R-tile
  const int lr = threadIdx.x >> 4;             // 0..15
  const int lc4 = (threadIdx.x & 15) * 4;
  #pragma unroll
  for (int i = 0; i < 4; ++i) {
    const int r = lr + i * 16;
    const float4 v = *(const float4*)(in + (long)(by * 64 + r) * C + bx * 64 + lc4);
    t[r][lc4] = v.x; t[r][lc4 + 1] = v.y; t[r][lc4 + 2] = v.z; t[r][lc4 + 3] = v.w;
  }
  __syncthreads();
  const int oc = threadIdx.x >> 4;
  const int or4 = (threadIdx.x & 15) * 4;
  #pragma unroll
  for (int i = 0; i < 4; ++i) {
    const int c = oc + i * 16;
    bf16x4 v;
    #pragma unroll
    for (int j = 0; j < 4; ++j) v[j] = (bf16)t[or4 + j][c];
    *(bf16x4*)(out + (long)(bx * 64 + c) * R + by * 64 + or4) = v;
  }
}

// ---------------------------------------------------------------------------
// Vectorized W1/W2 interleaved transpose: in [4096][11008] f32, col j ->
// out row ((j>>4)<<5)+off+(j&15) (off: W1=0, W2=16), cols = k (4096) bf16.
// ---------------------------------------------------------------------------
__global__ __launch_bounds__(256) void w12trans_kernel(
    const float* __restrict__ in, bf16* __restrict__ out, int off) {
  __shared__ float t[64][65];   // [k_local][j_local]
  const int bx = blockIdx.x, by = blockIdx.y;
  const int lk = threadIdx.x >> 4;
  const int lj4 = (threadIdx.x & 15) * 4;
  #pragma unroll
  for (int i = 0; i < 4; ++i) {
    const int k = lk + i * 16;
    const float4 v = *(const float4*)(in + (long)(by * 64 + k) * 11008 + bx * 64 + lj4);
    t[k][lj4] = v.x; t[k][lj4 + 1] = v.y; t[k][lj4 + 2] = v.z; t[k][lj4 + 3] = v.w;
  }
  __syncthreads();
  const int oj = threadIdx.x >> 4;
  const int ok4 = (threadIdx.x & 15) * 4;
  #pragma unroll
  for (int i = 0; i < 4; ++i) {
    const int j = bx * 64 + oj + i * 16;
    const int r = ((j >> 4) << 5) + off + (j & 15);
    bf16x4 v;
    #pragma unroll
    for (int jj = 0; jj < 4; ++jj) v[jj] = (bf16)t[ok4 + jj][oj + i * 16];
    *(bf16x4*)(out + (long)r * 4096 + by * 64 + ok4) = v;
  }
}

// ---------------------------------------------------------------------------
__global__ __launch_bounds__(256) void rope_table_kernel(float* __restrict__ cosT,
                                                         float* __restrict__ sinT) {
  const int idx = blockIdx.x * 256 + threadIdx.x;
  const int i = idx & 63, s = idx >> 6;
  const float inv = powf(10000.f, -(float)i / 64.f);
  const float ang = (float)s * inv;
  cosT[idx] = cosf(ang);
  sinT[idx] = sinf(ang);
}

// ---------------------------------------------------------------------------
// Flash attention, causal. Block=(qb,head), 4 waves x 16 q-rows.
// K/V double-buffered (drift): stage tile tb+1 at tile top, one barrier/tile.
// ---------------------------------------------------------------------------
__global__ __launch_bounds__(256) void attn_kernel(
    const bf16* __restrict__ qh, const bf16* __restrict__ kh,
    const bf16* __restrict__ vt, bf16* __restrict__ outb) {
  constexpr int S = 2048;
  const int qb = blockIdx.x, head = blockIdx.y;
  const int tid = threadIdx.x, wave = tid >> 6, lane = tid & 63;
  __shared__ bf16 Ks[2][64 * 128];
  __shared__ bf16 Vs[2][128 * 64];
  __shared__ bf16 Plds[4][16 * 64];
  const bf16* qhh = qh + (long)head * S * 128;
  const bf16* khh = kh + (long)head * S * 128;
  const bf16* vth = vt + (long)head * 128 * S;

  const int l15 = lane & 15, l4 = lane >> 4;
  const int qrow = qb * 64 + wave * 16 + l15;
  bf16x8 qf[4];
  #pragma unroll
  for (int kf = 0; kf < 4; ++kf)
    qf[kf] = *(const bf16x8*)(qhh + (long)qrow * 128 + kf * 32 + l4 * 8);

  auto stageKV = [&](int tb, int buf) {
    #pragma unroll
    for (int i = 0; i < 4; ++i) {
      const int c = wave + 4 * i;
      gload_lds16(khh + (long)(tb * 64 + c * 4 + l4) * 128 + l15 * 8, Ks[buf] + c * 512);
      gload_lds16(vth + (long)(c * 8 + (lane >> 3)) * S + tb * 64 + (lane & 7) * 8, Vs[buf] + c * 512);
    }
  };

  float m_r[4], l_r[4];
  #pragma unroll
  for (int r = 0; r < 4; ++r) { m_r[r] = -INFINITY; l_r[r] = 0.f; }
  f32x4 oacc[8] = {};
  const float scale = 0.08838834764831845f;

  stageKV(0, 0);
  __syncthreads();

  for (int tb = 0; tb <= qb; ++tb) {
    const int buf = tb & 1;
    if (tb < qb) stageKV(tb + 1, buf ^ 1);  // opposite buffer; fenced by barrier

    f32x4 sf[4];
    #pragma unroll
    for (int ft = 0; ft < 4; ++ft) {
      f32x4 acn = {};
      #pragma unroll
      for (int kf = 0; kf < 4; ++kf) {
        bf16x8 kfr = *(const bf16x8*)(Ks[buf] + (ft * 16 + l15) * 128 + kf * 32 + l4 * 8);
        acn = __builtin_amdgcn_mfma_f32_16x16x32_bf16(qf[kf], kfr, acn, 0, 0, 0);
      }
      #pragma unroll
      for (int r = 0; r < 4; ++r) sf[ft][r] = acn[r] * scale;
    }
    if (tb == qb) {
      #pragma unroll
      for (int ft = 0; ft < 4; ++ft) {
        const int t_l = ft * 16 + l15;
        #pragma unroll
        for (int r = 0; r < 4; ++r)
          if (t_l > wave * 16 + l4 * 4 + r) sf[ft][r] = -INFINITY;
      }
    }
    float scl[4];
    #pragma unroll
    for (int r = 0; r < 4; ++r) {
      float mx = fmaxf(fmaxf(sf[0][r], sf[1][r]), fmaxf(sf[2][r], sf[3][r]));
      mx = fmaxf(mx, __shfl_xor(mx, 1, 64));
      mx = fmaxf(mx, __shfl_xor(mx, 2, 64));
      mx = fmaxf(mx, __shfl_xor(mx, 4, 64));
      mx = fmaxf(mx, __shfl_xor(mx, 8, 64));
      const float mnew = fmaxf(m_r[r], mx);
      scl[r] = __expf(m_r[r] - mnew);
      m_r[r] = mnew;
      float rs = 0.f;
      #pragma unroll
      for (int ft = 0; ft < 4; ++ft) {
        const float pexp = __expf(sf[ft][r] - mnew);
        sf[ft][r] = pexp;
        rs += pexp;
      }
      rs += __shfl_xor(rs, 1, 64);
      rs += __shfl_xor(rs, 2, 64);
      rs += __shfl_xor(rs, 4, 64);
      rs += __shfl_xor(rs, 8, 64);
      l_r[r] = l_r[r] * scl[r] + rs;
    }
    #pragma unroll
    for (int ft = 0; ft < 4; ++ft)
      #pragma unroll
      for (int r = 0; r < 4; ++r)
        Plds[wave][(l4 * 4 + r) * 64 + ft * 16 + l15] = (bf16)sf[ft][r];
    #pragma unroll
    for (int fd = 0; fd < 8; ++fd)
      #pragma unroll
      for (int r = 0; r < 4; ++r) oacc[fd][r] *= scl[r];
    #pragma unroll
    for (int fd = 0; fd < 8; ++fd) {
      #pragma unroll
      for (int kt = 0; kt < 2; ++kt) {
        bf16x8 pa = *(const bf16x8*)(&Plds[wave][l15 * 64 + kt * 32 + l4 * 8]);
        bf16x8 vb = *(const bf16x8*)(Vs[buf] + (fd * 16 + l15) * 64 + kt * 32 + l4 * 8);
        oacc[fd] = __builtin_amdgcn_mfma_f32_16x16x32_bf16(pa, vb, oacc[fd], 0, 0, 0);
      }
    }
    __syncthreads();
  }
  #pragma unroll
  for (int fd = 0; fd < 8; ++fd) {
    #pragma unroll
    for (int r = 0; r < 4; ++r) {
      const long row = qb * 64 + wave * 16 + l4 * 4 + r;
      outb[row * 4096 + head * 128 + fd * 16 + l15] = (bf16)(oacc[fd][r] / l_r[r]);
    }
  }
}

// ---------------------------------------------------------------------------
extern "C" void kernel_launch(void* const* d_in, const int* in_sizes, int n_in,
                              void* d_out, int out_size, void* d_ws, size_t ws_size,
                              hipStream_t stream) {
  const float* X  = (const float*)d_in[0];
  const float* Wq = (const float*)d_in[1];
  const float* Wk = (const float*)d_in[2];
  const float* Wv = (const float*)d_in[3];
  const float* Wo = (const float*)d_in[4];
  const float* bo = (const float*)d_in[5];
  const float* g1 = (const float*)d_in[6];
  const float* g2 = (const float*)d_in[7];
  const float* W1 = (const float*)d_in[8];
  const float* W2 = (const float*)d_in[9];
  const float* W3 = (const float*)d_in[10];
  float* out = (float*)d_out;

  hipFuncSetAttribute((const void*)gemmd<1>, hipFuncAttributeMaxDynamicSharedMemorySize, 49152);
  hipFuncSetAttribute((const void*)gemmd<2>, hipFuncAttributeMaxDynamicSharedMemorySize, 49152);
  hipFuncSetAttribute((const void*)gemmd<3>, hipFuncAttributeMaxDynamicSharedMemorySize, 49152);
  hipFuncSetAttribute((const void*)gemmd<4>, hipFuncAttributeMaxDynamicSharedMemorySize, 49152);

  char* p = (char*)d_ws;
  auto alloc = [&](size_t bytes) {
    char* r = p;
    p += (bytes + 255) & ~(size_t)255;
    return r;
  };
  float* cosT = (float*)alloc(2048 * 64 * 4);
  float* sinT = (float*)alloc(2048 * 64 * 4);
  bf16* WqkvT = (bf16*)alloc(12288L * 4096 * 2);   // [12288][4096]; later g
  bf16* WoT  = (bf16*)alloc(4096L * 4096 * 2);
  bf16* W12T = (bf16*)alloc(22016L * 4096 * 2);    // interleaved [22016][4096]
  bf16* W3T  = (bf16*)alloc(4096L * 11008 * 2);
  bf16* qhB  = (bf16*)alloc(2048L * 4096 * 2);     // [32][2048][128]
  bf16* khB  = (bf16*)alloc(2048L * 4096 * 2);
  bf16* vtB  = (bf16*)alloc(2048L * 4096 * 2);     // [32][128][2048]
  bf16* hbuf = (bf16*)alloc(2048L * 4096 * 2);     // h, then attnb
  bf16* h2   = (bf16*)alloc(2048L * 4096 * 2);
  float* X2  = (float*)alloc(2048L * 4096 * 4);

  bf16* gsw = (bf16*)WqkvT;   // g [2048][11008] (WqkvT dead after QKV GEMM)
  bf16* attnb = hbuf;

  rope_table_kernel<<<512, 256, 0, stream>>>(cosT, sinT);
  wtrans_kernel<<<dim3(64, 64), 256, 0, stream>>>(Wq, WqkvT, 4096, 4096);
  wtrans_kernel<<<dim3(64, 64), 256, 0, stream>>>(Wk, WqkvT + 4096L * 4096, 4096, 4096);
  wtrans_kernel<<<dim3(64, 64), 256, 0, stream>>>(Wv, WqkvT + 2 * 4096L * 4096, 4096, 4096);
  wtrans_kernel<<<dim3(64, 64), 256, 0, stream>>>(Wo, WoT, 4096, 4096);
  w12trans_kernel<<<dim3(172, 64), 256, 0, stream>>>(W1, W12T, 0);
  w12trans_kernel<<<dim3(172, 64), 256, 0, stream>>>(W2, W12T, 16);
  wtrans_kernel<<<dim3(64, 172), 256, 0, stream>>>(W3, W3T, 11008, 4096);

  rmsnorm_kernel<<<2048, 256, 0, stream>>>(X, g1, hbuf, 4096);

  // q,k,v = rope/reorder(h @ [Wq|Wk|Wv])  — fused epilogue; 16x48 = 768 blocks
  gemmd<3><<<768, 512, 49152, stream>>>(hbuf, WqkvT, nullptr, nullptr, nullptr,
                                        cosT, sinT, qhB, khB, vtB,
                                        2048, 12288, 4096, 16);

  attn_kernel<<<dim3(32, 32), 256, 0, stream>>>(qhB, khB, vtB, attnb);

  // X2 = attn @ Wo + bo + X   (16x16 = 256 blocks)
  gemmd<1><<<256, 512, 49152, stream>>>(attnb, WoT, X2, bo, X,
                                        nullptr, nullptr, nullptr, nullptr, nullptr,
                                        2048, 4096, 4096, 16);

  rmsnorm_kernel<<<2048, 256, 0, stream>>>(X2, g2, h2, 4096);

  // g = silu(h2@W1) * (h2@W2)  — fused epilogue; 16x86 = 1376 blocks
  gemmd<4><<<1376, 512, 49152, stream>>>(h2, W12T, gsw, nullptr, nullptr,
                                         nullptr, nullptr, nullptr, nullptr, nullptr,
                                         2048, 22016, 4096, 16);

  // out = g @ W3 + X2   (16x16 = 256 blocks, K=11008)
  gemmd<2><<<256, 512, 49152, stream>>>(gsw, W3T, out, nullptr, X2,
                                        nullptr, nullptr, nullptr, nullptr, nullptr,
                                        2048, 4096, 11008, 16);
}

// Round 10
// 1381.496 us; speedup vs baseline: 1.1343x; 1.1343x over previous
//
#include <hip/hip_runtime.h>
#include <hip/hip_bf16.h>
#include <cstdint>
#include <cmath>

typedef __bf16 bf16;
typedef __attribute__((ext_vector_type(8))) __bf16 bf16x8;
typedef __attribute__((ext_vector_type(4))) __bf16 bf16x4;
typedef __attribute__((ext_vector_type(4))) float f32x4;

// async global->LDS, 16B per lane, dest = wave-uniform base (+ lane*16 by HW)
__device__ __forceinline__ void gload_lds16(const void* g, void* l) {
  __builtin_amdgcn_global_load_lds((__attribute__((address_space(1))) void*)g,
                                   (__attribute__((address_space(3))) void*)l,
                                   16, 0, 0);
}

#define BARX __builtin_amdgcn_s_barrier()
#define LGKM0 asm volatile("s_waitcnt lgkmcnt(0)" ::: "memory")
#define PRIO1 __builtin_amdgcn_s_setprio(1)
#define PRIO0 __builtin_amdgcn_s_setprio(0)

// ---------------------------------------------------------------------------
// 8-phase 256x256 GEMM with fused SwiGLU (W12 only). BK=64, 8 waves (2M x 4N;
// wave = 128 rows x 64 cols), 2 K-tiles per iteration, counted vmcnt.
// Reads: phase A = lda(mh0)+ldb (both halves across waves), C = lda(mh1);
// region free-times: B-halves after A's LGKM0, A-halves after C's LGKM0.
// Stages (iter j, t0=2j): A: A-h1(t1)  B: B-h0(t2)  C: B-h1(t2)  D: A-h0(t2)
//                         E: A-h1(t2)  F: B-h0(t3)  G: B-h1(t3)  H: A-h0(t3)
// each >=1 phase after its region's last read drained (LGKM0+barrier).
// vmcnt(6) at D retires <=A (t1 complete); vmcnt(6) at H retires <=E (t2
// complete); last iter D uses vmcnt(0). LDS 128K: buf*64K+isB*32K+half*16K+
// r*128+(chunk^(r&7))*16.
// ---------------------------------------------------------------------------
__global__ __launch_bounds__(512, 2) void gemm8_sw(
    const bf16* __restrict__ A, const bf16* __restrict__ Bt,
    bf16* __restrict__ gout, int M, int N, int K, int gm) {
  extern __shared__ char lds[];
  const int tid = threadIdx.x;
  const int wave = tid >> 6, lane = tid & 63;
  const int wr = wave >> 2, wc = wave & 3;     // 2M x 4N wave grid
  const int l15 = lane & 15, l4 = lane >> 4;
  const int qq = gridDim.x >> 3;
  const int wgid = (blockIdx.x & 7) * qq + (blockIdx.x >> 3);
  const int tm = wgid % gm, tn = wgid / gm;
  const long brow = (long)tm * 256, bcol = (long)tn * 256;
  const int NT = K >> 6;
  const bf16* Ab = A + brow * K;
  const bf16* Bb = Bt + bcol * K;

  f32x4 acc[8][4];
  #pragma unroll
  for (int i = 0; i < 8; ++i)
    #pragma unroll
    for (int j = 0; j < 4; ++j) acc[i][j] = (f32x4){0.f, 0.f, 0.f, 0.f};

  bf16x8 a[4][2], b[4][2];

  auto stage_half = [&](int T, int isB, int half) {
    const bf16* src = (isB ? Bb : Ab) + (long)(half * 128) * K + ((long)T << 6);
    char* dst = lds + (T & 1) * 65536 + isB * 32768 + half * 16384;
    #pragma unroll
    for (int i = 0; i < 2; ++i) {
      const int slot = i * 512 + tid, r = slot >> 3, c = slot & 7;
      gload_lds16(src + (long)r * K + ((c ^ (r & 7)) << 3), dst + slot * 16);
    }
  };
  auto lda = [&](int buf, int mh) {
    #pragma unroll
    for (int mf = 0; mf < 4; ++mf) {
      const int rr = mh * 64 + mf * 16 + l15;
      const char* base = lds + buf * 65536 + wr * 16384 + rr * 128;
      #pragma unroll
      for (int ks = 0; ks < 2; ++ks)
        a[mf][ks] = *(const bf16x8*)(base + (((ks * 4 + l4) ^ (rr & 7)) << 4));
    }
  };
  auto ldb = [&](int buf) {
    #pragma unroll
    for (int nf = 0; nf < 4; ++nf) {
      const int rr = (wc & 1) * 64 + nf * 16 + l15;
      const char* base = lds + buf * 65536 + 32768 + (wc >> 1) * 16384 + rr * 128;
      #pragma unroll
      for (int ks = 0; ks < 2; ++ks)
        b[nf][ks] = *(const bf16x8*)(base + (((ks * 4 + l4) ^ (rr & 7)) << 4));
    }
  };

  #define QMFMA(MH, NH) do {                                                   \
    _Pragma("unroll") for (int ks = 0; ks < 2; ++ks)                            \
    _Pragma("unroll") for (int mf = 0; mf < 4; ++mf)                            \
    _Pragma("unroll") for (int nf = 0; nf < 2; ++nf)                            \
      acc[(MH)*4+mf][(NH)*2+nf] = __builtin_amdgcn_mfma_f32_16x16x32_bf16(      \
          a[mf][ks], b[(NH)*2+nf][ks], acc[(MH)*4+mf][(NH)*2+nf], 0, 0, 0);     \
  } while (0)

  // prologue: t0 all 4 halves + t1 {B-h0,B-h1,A-h0}; drain t0, keep t1 in flight
  stage_half(0, 0, 0); stage_half(0, 0, 1); stage_half(0, 1, 0); stage_half(0, 1, 1);
  stage_half(1, 1, 0); stage_half(1, 1, 1); stage_half(1, 0, 0);
  asm volatile("s_waitcnt vmcnt(6)" ::: "memory");
  BARX;

  const int NI = NT >> 1;
  for (int j = 0; j < NI; ++j) {
    const int t0 = 2 * j;
    const bool s = (t0 + 2 < NT);
    // Phase A
    lda(0, 0); ldb(0);
    stage_half(t0 + 1, 0, 1);
    BARX; PRIO1; QMFMA(0, 0); PRIO0; LGKM0; BARX;
    // Phase B
    if (s) stage_half(t0 + 2, 1, 0);
    BARX; PRIO1; QMFMA(0, 1); PRIO0; BARX;
    // Phase C
    lda(0, 1);
    if (s) stage_half(t0 + 2, 1, 1);
    BARX; PRIO1; QMFMA(1, 0); PRIO0; LGKM0; BARX;
    // Phase D
    if (s) stage_half(t0 + 2, 0, 0);
    BARX; PRIO1; QMFMA(1, 1); PRIO0;
    if (s) asm volatile("s_waitcnt vmcnt(6)" ::: "memory");
    else   asm volatile("s_waitcnt vmcnt(0)" ::: "memory");
    BARX;
    // Phase E
    lda(1, 0); ldb(1);
    if (s) stage_half(t0 + 2, 0, 1);
    BARX; PRIO1; QMFMA(0, 0); PRIO0; LGKM0; BARX;
    // Phase F
    if (s) stage_half(t0 + 3, 1, 0);
    BARX; PRIO1; QMFMA(0, 1); PRIO0; BARX;
    // Phase G
    lda(1, 1);
    if (s) stage_half(t0 + 3, 1, 1);
    BARX; PRIO1; QMFMA(1, 0); PRIO0; LGKM0; BARX;
    // Phase H
    if (s) stage_half(t0 + 3, 0, 0);
    BARX; PRIO1; QMFMA(1, 1); PRIO0;
    if (s) asm volatile("s_waitcnt vmcnt(6)" ::: "memory");
    BARX;
  }
  #undef QMFMA

  // fused SwiGLU epilogue on 16-interleaved W12 -> g [s][11008]
  #pragma unroll
  for (int mf = 0; mf < 8; ++mf) {
    #pragma unroll
    for (int rj = 0; rj < 4; ++rj) {
      const int sA = (int)brow + wr * 128 + mf * 16 + l4 * 4 + rj;
      bf16* gr = gout + (long)sA * 11008;
      #pragma unroll
      for (int q = 0; q < 2; ++q) {
        const int col = (int)bcol + wc * 64 + q * 32 + l15;
        const int jj = ((col >> 5) << 4) + l15;
        const float x1 = acc[mf][2 * q][rj], x2 = acc[mf][2 * q + 1][rj];
        const float sg = x1 / (1.f + __expf(-x1));
        gr[jj] = (bf16)(sg * x2);
      }
    }
  }
}

// ---------------------------------------------------------------------------
// Drift GEMM (round-7 proven): BM x 256 tile, BK=64, 8 waves (4M x 2N: wave =
// BM/4 rows x 128 cols), dbuf LDS, one __syncthreads per K-tile, full-tile
// prefetch front-loaded. C = A[M,K] @ Bt^T.
// EPI 1: f32 = acc+bias[col]+resid (Wo). EPI 2: f32 = acc+resid (W3).
// EPI 3: QKV fused RoPE + head reorder: q,k -> [h][s][128], v -> [h][128][s]
// ---------------------------------------------------------------------------
template<int BM, int EPI>
__global__ __launch_bounds__(512, 2) void gemmd(
    const bf16* __restrict__ A, const bf16* __restrict__ Bt, void* __restrict__ Cv,
    const float* __restrict__ bias, const float* __restrict__ resid,
    const float* __restrict__ cosT, const float* __restrict__ sinT,
    bf16* __restrict__ q_out, bf16* __restrict__ k_out, bf16* __restrict__ v_out,
    int M, int N, int K, int gm) {
  extern __shared__ char lds[];
  constexpr int ASZ = BM * 128;
  constexpr int BUFS = ASZ + 32768;
  constexpr int MF = BM / 64;
  constexpr int LA = BM / 64;

  const int tid = threadIdx.x;
  const int wave = tid >> 6, lane = tid & 63;
  const int wr = wave >> 1, wc = wave & 1;   // 4M x 2N wave grid
  const int l15 = lane & 15, l4 = lane >> 4;
  const int qq = gridDim.x >> 3;
  const int wgid = (blockIdx.x & 7) * qq + (blockIdx.x >> 3);
  const int tm = wgid % gm, tn = wgid / gm;
  const long brow = (long)tm * BM, bcol = (long)tn * 256;
  const int NT = K >> 6;
  const bf16* Ab = A + brow * K;
  const bf16* Bb = Bt + bcol * K;

  f32x4 acc[MF][8];
  #pragma unroll
  for (int i = 0; i < MF; ++i)
    #pragma unroll
    for (int j = 0; j < 8; ++j) acc[i][j] = (f32x4){0.f, 0.f, 0.f, 0.f};

  bf16x8 a[MF][2], b[8][2];

  auto stage = [&](int T) {
    const long kofs = (long)T << 6;
    char* wb = lds + (T & 1) * BUFS;
    #pragma unroll
    for (int i = 0; i < LA; ++i) {
      const int slot = i * 512 + tid, r = slot >> 3, c0 = slot & 7;
      gload_lds16(Ab + (long)r * K + kofs + ((c0 ^ (r & 7)) << 3), wb + slot * 16);
    }
    #pragma unroll
    for (int i = 0; i < 4; ++i) {
      const int slot = i * 512 + tid, r = slot >> 3, c0 = slot & 7;
      gload_lds16(Bb + (long)r * K + kofs + ((c0 ^ (r & 7)) << 3), wb + ASZ + slot * 16);
    }
  };

  stage(0);
  __syncthreads();

  for (int g = 0; g < NT; ++g) {
    const int pg = (g & 1) * BUFS;
    if (g + 1 < NT) stage(g + 1);   // writes opposite buffer; fenced by barrier
    #pragma unroll
    for (int nf = 0; nf < 8; ++nf)
      #pragma unroll
      for (int ks = 0; ks < 2; ++ks) {
        const int r = wc * 128 + nf * 16 + l15;
        b[nf][ks] = *(const bf16x8*)(lds + pg + ASZ + r * 128 + (((ks * 4 + l4) ^ (r & 7)) << 4));
      }
    #pragma unroll
    for (int mf = 0; mf < MF; ++mf)
      #pragma unroll
      for (int ks = 0; ks < 2; ++ks) {
        const int r = wr * (BM / 4) + mf * 16 + l15;
        a[mf][ks] = *(const bf16x8*)(lds + pg + r * 128 + (((ks * 4 + l4) ^ (r & 7)) << 4));
      }
    PRIO1;
    #pragma unroll
    for (int ks = 0; ks < 2; ++ks)
      #pragma unroll
      for (int mf = 0; mf < MF; ++mf)
        #pragma unroll
        for (int nf = 0; nf < 8; ++nf)
          acc[mf][nf] = __builtin_amdgcn_mfma_f32_16x16x32_bf16(
              a[mf][ks], b[nf][ks], acc[mf][nf], 0, 0, 0);
    PRIO0;
    __syncthreads();
  }

  if (EPI == 1 || EPI == 2) {
    #pragma unroll
    for (int mf = 0; mf < MF; ++mf) {
      const long row0 = brow + wr * (BM / 4) + mf * 16 + l4 * 4;
      #pragma unroll
      for (int nf = 0; nf < 8; ++nf) {
        const long col = bcol + wc * 128 + nf * 16 + l15;
        #pragma unroll
        for (int rj = 0; rj < 4; ++rj) {
          const long idx = (row0 + rj) * N + col;
          const float v = acc[mf][nf][rj];
          if (EPI == 1) ((float*)Cv)[idx] = v + bias[col] + resid[idx];
          else          ((float*)Cv)[idx] = v + resid[idx];
        }
      }
    }
  } else if (EPI == 3) {
    const int region = (int)(bcol >> 12);           // 0=Q, 1=K, 2=V
    const int hc = (int)(bcol & 4095) + wc * 128;
    const int h = hc >> 7;
    if (region < 2) {
      bf16* dh = (region == 0 ? q_out : k_out) + (long)h * 2048 * 128;
      #pragma unroll
      for (int mf = 0; mf < MF; ++mf) {
        #pragma unroll
        for (int rj = 0; rj < 4; ++rj) {
          const int s = (int)brow + wr * (BM / 4) + mf * 16 + l4 * 4 + rj;
          const float* cr = cosT + s * 64;
          const float* sr = sinT + s * 64;
          #pragma unroll
          for (int nfp = 0; nfp < 4; ++nfp) {
            const int d = nfp * 16 + l15;
            const float c = cr[d], sn = sr[d];
            const float x1 = acc[mf][nfp][rj], x2 = acc[mf][nfp + 4][rj];
            dh[(long)s * 128 + d]      = (bf16)(x1 * c - x2 * sn);
            dh[(long)s * 128 + d + 64] = (bf16)(x2 * c + x1 * sn);
          }
        }
      }
    } else {
      bf16* dh = v_out + (long)h * 128 * 2048;
      #pragma unroll
      for (int mf = 0; mf < MF; ++mf) {
        const int s0 = (int)brow + wr * (BM / 4) + mf * 16 + l4 * 4;
        #pragma unroll
        for (int nf = 0; nf < 8; ++nf) {
          const int d = nf * 16 + l15;
          bf16x4 v;
          #pragma unroll
          for (int rj = 0; rj < 4; ++rj) v[rj] = (bf16)acc[mf][nf][rj];
          *(bf16x4*)(dh + (long)d * 2048 + s0) = v;
        }
      }
    }
  }
}

// ---------------------------------------------------------------------------
// RMSNorm: one block per row of [2048][4096] f32 -> bf16
// ---------------------------------------------------------------------------
__global__ __launch_bounds__(256) void rmsnorm_kernel(
    const float* __restrict__ X, const float* __restrict__ gamma,
    bf16* __restrict__ out, int D) {
  const int row = blockIdx.x;
  const float* xr = X + (long)row * D;
  float ss = 0.f;
  for (int i = threadIdx.x * 4; i < D; i += 1024) {
    float4 v = *(const float4*)(xr + i);
    ss += v.x * v.x + v.y * v.y + v.z * v.z + v.w * v.w;
  }
  #pragma unroll
  for (int off = 32; off; off >>= 1) ss += __shfl_down(ss, off, 64);
  __shared__ float wsum[4];
  if ((threadIdx.x & 63) == 0) wsum[threadIdx.x >> 6] = ss;
  __syncthreads();
  const float tot = wsum[0] + wsum[1] + wsum[2] + wsum[3];
  const float scale = rsqrtf(1e-7f + tot / (float)D);
  bf16* orow = out + (long)row * D;
  for (int i = threadIdx.x * 4; i < D; i += 1024) {
    float4 v = *(const float4*)(xr + i);
    float4 g = *(const float4*)(gamma + i);
    orow[i]     = (bf16)(v.x * scale * g.x);
    orow[i + 1] = (bf16)(v.y * scale * g.y);
    orow[i + 2] = (bf16)(v.z * scale * g.z);
    orow[i + 3] = (bf16)(v.w * scale * g.w);
  }
}

// ---------------------------------------------------------------------------
// Vectorized weight transpose + f32->bf16: in [R][C] f32 -> out [C][R] bf16.
// ---------------------------------------------------------------------------
__global__ __launch_bounds__(256) void wtrans_kernel(
    const float* __restrict__ in, bf16* __restrict__ out, int R, int C) {
  __shared__ float t[64][65];
  const int bx = blockIdx.x, by = blockIdx.y;
  const int lr = threadIdx.x >> 4;
  const int lc4 = (threadIdx.x & 15) * 4;
  #pragma unroll
  for (int i = 0; i < 4; ++i) {
    const int r = lr + i * 16;
    const float4 v = *(const float4*)(in + (long)(by * 64 + r) * C + bx * 64 + lc4);
    t[r][lc4] = v.x; t[r][lc4 + 1] = v.y; t[r][lc4 + 2] = v.z; t[r][lc4 + 3] = v.w;
  }
  __syncthreads();
  const int oc = threadIdx.x >> 4;
  const int or4 = (threadIdx.x & 15) * 4;
  #pragma unroll
  for (int i = 0; i < 4; ++i) {
    const int c = oc + i * 16;
    bf16x4 v;
    #pragma unroll
    for (int j = 0; j < 4; ++j) v[j] = (bf16)t[or4 + j][c];
    *(bf16x4*)(out + (long)(bx * 64 + c) * R + by * 64 + or4) = v;
  }
}

// ---------------------------------------------------------------------------
// Vectorized W1/W2 interleaved transpose: col j -> out row ((j>>4)<<5)+off+(j&15)
// ---------------------------------------------------------------------------
__global__ __launch_bounds__(256) void w12trans_kernel(
    const float* __restrict__ in, bf16* __restrict__ out, int off) {
  __shared__ float t[64][65];
  const int bx = blockIdx.x, by = blockIdx.y;
  const int lk = threadIdx.x >> 4;
  const int lj4 = (threadIdx.x & 15) * 4;
  #pragma unroll
  for (int i = 0; i < 4; ++i) {
    const int k = lk + i * 16;
    const float4 v = *(const float4*)(in + (long)(by * 64 + k) * 11008 + bx * 64 + lj4);
    t[k][lj4] = v.x; t[k][lj4 + 1] = v.y; t[k][lj4 + 2] = v.z; t[k][lj4 + 3] = v.w;
  }
  __syncthreads();
  const int oj = threadIdx.x >> 4;
  const int ok4 = (threadIdx.x & 15) * 4;
  #pragma unroll
  for (int i = 0; i < 4; ++i) {
    const int j = bx * 64 + oj + i * 16;
    const int r = ((j >> 4) << 5) + off + (j & 15);
    bf16x4 v;
    #pragma unroll
    for (int jj = 0; jj < 4; ++jj) v[jj] = (bf16)t[ok4 + jj][oj + i * 16];
    *(bf16x4*)(out + (long)r * 4096 + by * 64 + ok4) = v;
  }
}

// ---------------------------------------------------------------------------
__global__ __launch_bounds__(256) void rope_table_kernel(float* __restrict__ cosT,
                                                         float* __restrict__ sinT) {
  const int idx = blockIdx.x * 256 + threadIdx.x;
  const int i = idx & 63, s = idx >> 6;
  const float inv = powf(10000.f, -(float)i / 64.f);
  const float ang = (float)s * inv;
  cosT[idx] = cosf(ang);
  sinT[idx] = sinf(ang);
}

// ---------------------------------------------------------------------------
// Flash attention, causal. Block=(qb,head), 4 waves x 16 q-rows. K/V dbuf.
// ---------------------------------------------------------------------------
__global__ __launch_bounds__(256) void attn_kernel(
    const bf16* __restrict__ qh, const bf16* __restrict__ kh,
    const bf16* __restrict__ vt, bf16* __restrict__ outb) {
  constexpr int S = 2048;
  const int qb = blockIdx.x, head = blockIdx.y;
  const int tid = threadIdx.x, wave = tid >> 6, lane = tid & 63;
  __shared__ bf16 Ks[2][64 * 128];
  __shared__ bf16 Vs[2][128 * 64];
  __shared__ bf16 Plds[4][16 * 64];
  const bf16* qhh = qh + (long)head * S * 128;
  const bf16* khh = kh + (long)head * S * 128;
  const bf16* vth = vt + (long)head * 128 * S;

  const int l15 = lane & 15, l4 = lane >> 4;
  const int qrow = qb * 64 + wave * 16 + l15;
  bf16x8 qf[4];
  #pragma unroll
  for (int kf = 0; kf < 4; ++kf)
    qf[kf] = *(const bf16x8*)(qhh + (long)qrow * 128 + kf * 32 + l4 * 8);

  auto stageKV = [&](int tb, int buf) {
    #pragma unroll
    for (int i = 0; i < 4; ++i) {
      const int c = wave + 4 * i;
      gload_lds16(khh + (long)(tb * 64 + c * 4 + l4) * 128 + l15 * 8, Ks[buf] + c * 512);
      gload_lds16(vth + (long)(c * 8 + (lane >> 3)) * S + tb * 64 + (lane & 7) * 8, Vs[buf] + c * 512);
    }
  };

  float m_r[4], l_r[4];
  #pragma unroll
  for (int r = 0; r < 4; ++r) { m_r[r] = -INFINITY; l_r[r] = 0.f; }
  f32x4 oacc[8] = {};
  const float scale = 0.08838834764831845f;

  stageKV(0, 0);
  __syncthreads();

  for (int tb = 0; tb <= qb; ++tb) {
    const int buf = tb & 1;
    if (tb < qb) stageKV(tb + 1, buf ^ 1);

    f32x4 sf[4];
    #pragma unroll
    for (int ft = 0; ft < 4; ++ft) {
      f32x4 acn = {};
      #pragma unroll
      for (int kf = 0; kf < 4; ++kf) {
        bf16x8 kfr = *(const bf16x8*)(Ks[buf] + (ft * 16 + l15) * 128 + kf * 32 + l4 * 8);
        acn = __builtin_amdgcn_mfma_f32_16x16x32_bf16(qf[kf], kfr, acn, 0, 0, 0);
      }
      #pragma unroll
      for (int r = 0; r < 4; ++r) sf[ft][r] = acn[r] * scale;
    }
    if (tb == qb) {
      #pragma unroll
      for (int ft = 0; ft < 4; ++ft) {
        const int t_l = ft * 16 + l15;
        #pragma unroll
        for (int r = 0; r < 4; ++r)
          if (t_l > wave * 16 + l4 * 4 + r) sf[ft][r] = -INFINITY;
      }
    }
    float scl[4];
    #pragma unroll
    for (int r = 0; r < 4; ++r) {
      float mx = fmaxf(fmaxf(sf[0][r], sf[1][r]), fmaxf(sf[2][r], sf[3][r]));
      mx = fmaxf(mx, __shfl_xor(mx, 1, 64));
      mx = fmaxf(mx, __shfl_xor(mx, 2, 64));
      mx = fmaxf(mx, __shfl_xor(mx, 4, 64));
      mx = fmaxf(mx, __shfl_xor(mx, 8, 64));
      const float mnew = fmaxf(m_r[r], mx);
      scl[r] = __expf(m_r[r] - mnew);
      m_r[r] = mnew;
      float rs = 0.f;
      #pragma unroll
      for (int ft = 0; ft < 4; ++ft) {
        const float pexp = __expf(sf[ft][r] - mnew);
        sf[ft][r] = pexp;
        rs += pexp;
      }
      rs += __shfl_xor(rs, 1, 64);
      rs += __shfl_xor(rs, 2, 64);
      rs += __shfl_xor(rs, 4, 64);
      rs += __shfl_xor(rs, 8, 64);
      l_r[r] = l_r[r] * scl[r] + rs;
    }
    #pragma unroll
    for (int ft = 0; ft < 4; ++ft)
      #pragma unroll
      for (int r = 0; r < 4; ++r)
        Plds[wave][(l4 * 4 + r) * 64 + ft * 16 + l15] = (bf16)sf[ft][r];
    #pragma unroll
    for (int fd = 0; fd < 8; ++fd)
      #pragma unroll
      for (int r = 0; r < 4; ++r) oacc[fd][r] *= scl[r];
    #pragma unroll
    for (int fd = 0; fd < 8; ++fd) {
      #pragma unroll
      for (int kt = 0; kt < 2; ++kt) {
        bf16x8 pa = *(const bf16x8*)(&Plds[wave][l15 * 64 + kt * 32 + l4 * 8]);
        bf16x8 vb = *(const bf16x8*)(Vs[buf] + (fd * 16 + l15) * 64 + kt * 32 + l4 * 8);
        oacc[fd] = __builtin_amdgcn_mfma_f32_16x16x32_bf16(pa, vb, oacc[fd], 0, 0, 0);
      }
    }
    __syncthreads();
  }
  #pragma unroll
  for (int fd = 0; fd < 8; ++fd) {
    #pragma unroll
    for (int r = 0; r < 4; ++r) {
      const long row = qb * 64 + wave * 16 + l4 * 4 + r;
      outb[row * 4096 + head * 128 + fd * 16 + l15] = (bf16)(oacc[fd][r] / l_r[r]);
    }
  }
}

// ---------------------------------------------------------------------------
extern "C" void kernel_launch(void* const* d_in, const int* in_sizes, int n_in,
                              void* d_out, int out_size, void* d_ws, size_t ws_size,
                              hipStream_t stream) {
  const float* X  = (const float*)d_in[0];
  const float* Wq = (const float*)d_in[1];
  const float* Wk = (const float*)d_in[2];
  const float* Wv = (const float*)d_in[3];
  const float* Wo = (const float*)d_in[4];
  const float* bo = (const float*)d_in[5];
  const float* g1 = (const float*)d_in[6];
  const float* g2 = (const float*)d_in[7];
  const float* W1 = (const float*)d_in[8];
  const float* W2 = (const float*)d_in[9];
  const float* W3 = (const float*)d_in[10];
  float* out = (float*)d_out;

  hipFuncSetAttribute((const void*)gemmd<256, 3>, hipFuncAttributeMaxDynamicSharedMemorySize, 131072);
  hipFuncSetAttribute((const void*)gemm8_sw, hipFuncAttributeMaxDynamicSharedMemorySize, 131072);
  hipFuncSetAttribute((const void*)gemmd<128, 1>, hipFuncAttributeMaxDynamicSharedMemorySize, 98304);
  hipFuncSetAttribute((const void*)gemmd<128, 2>, hipFuncAttributeMaxDynamicSharedMemorySize, 98304);

  char* p = (char*)d_ws;
  auto alloc = [&](size_t bytes) {
    char* r = p;
    p += (bytes + 255) & ~(size_t)255;
    return r;
  };
  float* cosT = (float*)alloc(2048 * 64 * 4);
  float* sinT = (float*)alloc(2048 * 64 * 4);
  bf16* WqkvT = (bf16*)alloc(12288L * 4096 * 2);   // [12288][4096]; later g
  bf16* WoT  = (bf16*)alloc(4096L * 4096 * 2);
  bf16* W12T = (bf16*)alloc(22016L * 4096 * 2);    // interleaved [22016][4096]
  bf16* W3T  = (bf16*)alloc(4096L * 11008 * 2);
  bf16* qhB  = (bf16*)alloc(2048L * 4096 * 2);     // [32][2048][128]
  bf16* khB  = (bf16*)alloc(2048L * 4096 * 2);
  bf16* vtB  = (bf16*)alloc(2048L * 4096 * 2);     // [32][128][2048]
  bf16* hbuf = (bf16*)alloc(2048L * 4096 * 2);     // h, then attnb
  bf16* h2   = (bf16*)alloc(2048L * 4096 * 2);
  float* X2  = (float*)alloc(2048L * 4096 * 4);

  bf16* gsw = (bf16*)WqkvT;   // g [2048][11008] (WqkvT dead after QKV GEMM)
  bf16* attnb = hbuf;

  rope_table_kernel<<<512, 256, 0, stream>>>(cosT, sinT);
  wtrans_kernel<<<dim3(64, 64), 256, 0, stream>>>(Wq, WqkvT, 4096, 4096);
  wtrans_kernel<<<dim3(64, 64), 256, 0, stream>>>(Wk, WqkvT + 4096L * 4096, 4096, 4096);
  wtrans_kernel<<<dim3(64, 64), 256, 0, stream>>>(Wv, WqkvT + 2 * 4096L * 4096, 4096, 4096);
  wtrans_kernel<<<dim3(64, 64), 256, 0, stream>>>(Wo, WoT, 4096, 4096);
  w12trans_kernel<<<dim3(172, 64), 256, 0, stream>>>(W1, W12T, 0);
  w12trans_kernel<<<dim3(172, 64), 256, 0, stream>>>(W2, W12T, 16);
  wtrans_kernel<<<dim3(64, 172), 256, 0, stream>>>(W3, W3T, 11008, 4096);

  rmsnorm_kernel<<<2048, 256, 0, stream>>>(X, g1, hbuf, 4096);

  // q,k,v = rope/reorder(h @ [Wq|Wk|Wv])  — drift-256, fused epilogue
  gemmd<256, 3><<<384, 512, 131072, stream>>>(hbuf, WqkvT, nullptr, nullptr, nullptr,
                                              cosT, sinT, qhB, khB, vtB,
                                              2048, 12288, 4096, 8);

  attn_kernel<<<dim3(32, 32), 256, 0, stream>>>(qhB, khB, vtB, attnb);

  // X2 = attn @ Wo + bo + X   (drift-128)
  gemmd<128, 1><<<256, 512, 98304, stream>>>(attnb, WoT, X2, bo, X,
                                             nullptr, nullptr, nullptr, nullptr, nullptr,
                                             2048, 4096, 4096, 16);

  rmsnorm_kernel<<<2048, 256, 0, stream>>>(X2, g2, h2, 4096);

  // g = silu(h2@W1) * (h2@W2)  — 8-phase experiment on the biggest GEMM
  gemm8_sw<<<688, 512, 131072, stream>>>(h2, W12T, gsw, 2048, 22016, 4096, 8);

  // out = g @ W3 + X2   (drift-128)
  gemmd<128, 2><<<256, 512, 98304, stream>>>(gsw, W3T, out, nullptr, X2,
                                             nullptr, nullptr, nullptr, nullptr, nullptr,
                                             2048, 4096, 11008, 16);
}